// Round 16
// baseline (249.290 us; speedup 1.0000x reference)
//
#include <hip/hip_runtime.h>
#include <hip/hip_bf16.h>

#define NUM_HEADS 4
#define HD 256
#define QD 256
#define VD 256
#define B_SZ 32
#define N_NODES 8192
#define NEG_SLOPE 0.2f
#define CH 16
#define KSTRIDE 1040

typedef short bf16x8 __attribute__((ext_vector_type(8)));
typedef float f32x4 __attribute__((ext_vector_type(4)));

static __device__ __forceinline__ unsigned short f2bf(float f) {
    __hip_bfloat16 h = __float2bfloat16(f);
    return *reinterpret_cast<unsigned short*>(&h);
}

static __device__ __forceinline__ void gload_lds16(const float* g, void* l) {
    __builtin_amdgcn_global_load_lds(
        (const __attribute__((address_space(1))) void*)g,
        (__attribute__((address_space(3))) void*)l, 16, 0, 0);
}

// ---------------------------------------------------------------------------
// Kernel 1: prep (unchanged)
// ---------------------------------------------------------------------------
__global__ __launch_bounds__(256)
void prep_kernel(const float* __restrict__ query,
                 const float* __restrict__ Wq,
                 const float* __restrict__ bq,
                 unsigned short* __restrict__ WqP,
                 float* __restrict__ hqb) {
    int blk = blockIdx.x;
    int tid = threadIdx.x;
    if (blk < 32) {
        int b = blk, col = tid;
        float acc = 2.0f * bq[col];
#pragma unroll 16
        for (int k = 0; k < QD; ++k)
            acc += query[b * QD + k] * Wq[k * HD + col];
        hqb[b * HD + col] = acc;
    } else {
        int idx = blk - 32;
        int kstep = idx >> 2, g = idx & 3;
        int col = tid;
        int h = col >> 6, ct = (col >> 4) & 3, col16 = col & 15;
        unsigned short v[8];
#pragma unroll
        for (int j = 0; j < 8; ++j)
            v[j] = f2bf(Wq[(kstep * 32 + g * 8 + j) * HD + col]);
        *reinterpret_cast<uint4*>(
            WqP + kstep * 8192 + h * 2048 + ct * 512 + (g * 16 + col16) * 8) =
            *reinterpret_cast<uint4*>(v);
    }
}

// ---------------------------------------------------------------------------
// Kernel 2: template<V> ablation of the R15 fused kernel.
//  V0: full (real outputs).  V1: noSM (staging+MFMA+PV).  V2: stream-only
//  (staging skeleton + stub reads).  V3: compute-only (no in-loop staging).
// ---------------------------------------------------------------------------
template <int V>
__global__ __launch_bounds__(256, 2)
void fused_kernel(const float* __restrict__ key,
                  const float* __restrict__ value,
                  const unsigned short* __restrict__ WqP,
                  const float* __restrict__ hqb,
                  const float* __restrict__ avec,
                  float* __restrict__ s,
                  float* __restrict__ p_part,
                  float* __restrict__ pml,
                  int nch) {
    __shared__ __align__(16) char smem[2 * (CH * KSTRIDE) + 2 * (CH * 1024)];

    char* kb0 = smem;
    char* kb1 = smem + CH * KSTRIDE;
    char* vb0 = smem + 2 * CH * KSTRIDE;
    char* vb1 = vb0 + CH * 1024;

    int bid = blockIdx.x;
    int b = bid >> 4, strip = bid & 15;
    int tid = threadIdx.x;
    int w = tid >> 6, lane = tid & 63;
    int col16 = lane & 15, g = (lane >> 4) & 3;
    int h = w;
    int rowbase0 = strip * 512;

    bf16x8 bfr[8][4];
    {
        const unsigned short* wp0 = WqP + h * 2048 + (g * 16 + col16) * 8;
#pragma unroll
        for (int ks = 0; ks < 8; ++ks)
#pragma unroll
            for (int ct = 0; ct < 4; ++ct)
                bfr[ks][ct] = *reinterpret_cast<const bf16x8*>(wp0 + ks * 8192 + ct * 512);
    }
    float av16[4][4], hq16[4][4];
#pragma unroll
    for (int ct = 0; ct < 4; ++ct)
#pragma unroll
        for (int r = 0; r < 4; ++r) {
            int d = ct * 16 + g * 4 + r;
            av16[ct][r] = avec[d];
            hq16[ct][r] = hqb[b * HD + h * 64 + d];
        }

    float mr = -1e30f, lr = 0.f;
    f32x4 pa = (f32x4){0.f, 0.f, 0.f, 0.f};

    // prologue: stage chunk 0
    {
        int rb = rowbase0;
#pragma unroll
        for (int r = 0; r < 4; ++r) {
            int lr_ = w * 4 + r;
            gload_lds16(key + ((size_t)(b * N_NODES + rb + lr_)) * QD + lane * 4,
                        kb0 + lr_ * KSTRIDE);
            gload_lds16(value + ((size_t)(b * N_NODES + rb + lr_)) * VD + lane * 4,
                        vb0 + lr_ * 1024);
        }
    }
    if (V == 3) {   // compute-only: settle staging once, never load again
        asm volatile("s_waitcnt vmcnt(0)" ::: "memory");
        __builtin_amdgcn_s_barrier();
    }

    for (int t = 0; t < nch; ++t) {
        __builtin_amdgcn_s_barrier();
        if (V != 3) {
            if (t + 1 < nch) {
                char* kbn = ((t + 1) & 1) ? kb1 : kb0;
                char* vbn = ((t + 1) & 1) ? vb1 : vb0;
                int rb = rowbase0 + (t + 1) * CH;
#pragma unroll
                for (int r = 0; r < 4; ++r) {
                    int lr_ = w * 4 + r;
                    gload_lds16(key + ((size_t)(b * N_NODES + rb + lr_)) * QD + lane * 4,
                                kbn + lr_ * KSTRIDE);
                }
#pragma unroll
                for (int r = 0; r < 4; ++r) {
                    int lr_ = w * 4 + r;
                    gload_lds16(value + ((size_t)(b * N_NODES + rb + lr_)) * VD + lane * 4,
                                vbn + lr_ * 1024);
                }
                asm volatile("s_waitcnt vmcnt(8)" ::: "memory");
            } else {
                asm volatile("s_waitcnt vmcnt(0)" ::: "memory");
            }
        }
        __builtin_amdgcn_s_barrier();
        __builtin_amdgcn_sched_barrier(0);

        const char* kb = (V == 3) ? kb0 : ((t & 1) ? kb1 : kb0);
        const char* vb = (V == 3) ? vb0 : ((t & 1) ? vb1 : vb0);
        int n0c = rowbase0 + t * CH;

        if (V == 2) {
            // stream-only: minimal live consumption of both buffers
            f32x4 kx = *reinterpret_cast<const f32x4*>(kb + col16 * KSTRIDE + g * 32);
            f32x4 vx = *reinterpret_cast<const f32x4*>(vb + col16 * 1024 + g * 16);
            pa += kx;
            pa += vx;
            continue;
        }

        // ---- A-frags from key LDS
        bf16x8 a[8];
#pragma unroll
        for (int ks = 0; ks < 8; ++ks) {
            f32x4 lo = *reinterpret_cast<const f32x4*>(kb + col16 * KSTRIDE + ks * 128 + g * 32);
            f32x4 hi = *reinterpret_cast<const f32x4*>(kb + col16 * KSTRIDE + ks * 128 + g * 32 + 16);
            unsigned int u0, u1, u2, u3;
            asm("v_cvt_pk_bf16_f32 %0, %1, %2" : "=v"(u0) : "v"(lo[0]), "v"(lo[1]));
            asm("v_cvt_pk_bf16_f32 %0, %1, %2" : "=v"(u1) : "v"(lo[2]), "v"(lo[3]));
            asm("v_cvt_pk_bf16_f32 %0, %1, %2" : "=v"(u2) : "v"(hi[0]), "v"(hi[1]));
            asm("v_cvt_pk_bf16_f32 %0, %1, %2" : "=v"(u3) : "v"(hi[2]), "v"(hi[3]));
            uint4 tt = {u0, u1, u2, u3};
            a[ks] = *reinterpret_cast<bf16x8*>(&tt);
        }

        f32x4 acc[4];
#pragma unroll
        for (int ct = 0; ct < 4; ++ct) acc[ct] = (f32x4){0.f, 0.f, 0.f, 0.f};
#pragma unroll
        for (int ks = 0; ks < 8; ++ks)
#pragma unroll
            for (int ct = 0; ct < 4; ++ct)
                acc[ct] = __builtin_amdgcn_mfma_f32_16x16x32_bf16(bfr[ks][ct], a[ks], acc[ct], 0, 0, 0);

        float ep;
        if (V == 1) {
            // noSM: keep MFMA live without the softmax chain
            ep = (acc[0][0] + acc[1][1] + acc[2][2] + acc[3][3]) * 1e-20f;
        } else {
            float dot = 0.f;
#pragma unroll
            for (int ct = 0; ct < 4; ++ct) {
#pragma unroll
                for (int r = 0; r < 4; ++r) {
                    float pre = acc[ct][r] + hq16[ct][r];
                    float tv = fmaxf(pre, NEG_SLOPE * pre);
                    dot += av16[ct][r] * tv;
                }
            }
            dot += __shfl_xor(dot, 16, 64);
            dot += __shfl_xor(dot, 32, 64);

            if (V == 0 && lane < 16)
                s[((size_t)(b * NUM_HEADS + h)) * N_NODES + n0c + lane] = dot;

            float mc = dot;
            mc = fmaxf(mc, __shfl_xor(mc, 1, 64));
            mc = fmaxf(mc, __shfl_xor(mc, 2, 64));
            mc = fmaxf(mc, __shfl_xor(mc, 4, 64));
            mc = fmaxf(mc, __shfl_xor(mc, 8, 64));
            float mnew = fmaxf(mr, mc);
            ep = __expf(dot - mnew);
            float lc = ep;
            lc += __shfl_xor(lc, 1, 64);
            lc += __shfl_xor(lc, 2, 64);
            lc += __shfl_xor(lc, 4, 64);
            lc += __shfl_xor(lc, 8, 64);
            float scf = __expf(mr - mnew);
            pa *= scf;
            lr = lr * scf + lc;
            mr = mnew;
        }

        // ---- PV
#pragma unroll
        for (int n = 0; n < 16; ++n) {
            f32x4 v = *reinterpret_cast<const f32x4*>(vb + n * 1024 + lane * 16);
            float e = __shfl(ep, n, 64);
            pa += e * v;
        }
    }

    int slot = bid * 4 + w;
    *reinterpret_cast<f32x4*>(p_part + (size_t)slot * 256 + lane * 4) = pa;
    if (lane == 0) {
        pml[slot * 2] = mr;
        pml[slot * 2 + 1] = lr;
    }
}

// ---------------------------------------------------------------------------
// Kernel 3: final (unchanged)
// ---------------------------------------------------------------------------
__global__ __launch_bounds__(256)
void final_kernel(const float* __restrict__ p_part,
                  const float* __restrict__ pml,
                  const float* __restrict__ Wv,
                  const float* __restrict__ bv,
                  float* __restrict__ hout,
                  float* __restrict__ sc) {
    int bh = blockIdx.x;
    int b = bh >> 2, h = bh & 3;
    int tid = threadIdx.x;

    int slots[16];
    float mv[16], lv[16];
    float M = -1e30f;
#pragma unroll
    for (int i = 0; i < 16; ++i) {
        slots[i] = (b * 16 + i) * 4 + h;
        mv[i] = pml[slots[i] * 2];
        lv[i] = pml[slots[i] * 2 + 1];
        M = fmaxf(M, mv[i]);
    }
    float L = 0.f, acc = 0.f;
#pragma unroll
    for (int i = 0; i < 16; ++i) {
        float wf = __expf(mv[i] - M);
        L += wf * lv[i];
        acc += wf * p_part[(size_t)slots[i] * 256 + tid];
    }
    float invL = 1.0f / L;
    if (tid == 0) {
        sc[bh * 2] = M;
        sc[bh * 2 + 1] = invL;
    }
    __shared__ float ps[256];
    ps[tid] = acc * invL;
    __syncthreads();

    int d = tid & 63, kr = tid >> 6;
    float a2 = 0.f;
#pragma unroll 8
    for (int k = kr * 64; k < kr * 64 + 64; ++k)
        a2 += ps[k] * Wv[k * HD + h * 64 + d];
    __shared__ float rs[4][64];
    rs[kr][d] = a2;
    __syncthreads();
    if (tid < 64) {
        float o = bv[h * 64 + tid] + rs[0][tid] + rs[1][tid] + rs[2][tid] + rs[3][tid];
        hout[b * HD + h * 64 + tid] = fmaxf(o, 0.f);
    }
}

// ---------------------------------------------------------------------------
// Kernel 4: e-pass (unchanged)
// ---------------------------------------------------------------------------
__global__ __launch_bounds__(256)
void epass_kernel(const float* __restrict__ s,
                  const float* __restrict__ sc,
                  float* __restrict__ e_out) {
    int bid = blockIdx.x;
    int b = bid >> 5, t = bid & 31;
    int n = t * 256 + threadIdx.x;
    float4 ev;
#pragma unroll
    for (int h = 0; h < 4; ++h) {
        float M = sc[(b * 4 + h) * 2];
        float invL = sc[(b * 4 + h) * 2 + 1];
        float sv = s[((size_t)(b * 4 + h)) * N_NODES + n];
        (&ev.x)[h] = __expf(sv - M) * invL;
    }
    *reinterpret_cast<float4*>(e_out + ((size_t)(b * N_NODES + n)) * 4) = ev;
}

extern "C" void kernel_launch(void* const* d_in, const int* in_sizes, int n_in,
                              void* d_out, int out_size, void* d_ws, size_t ws_size,
                              hipStream_t stream) {
    const float* query = (const float*)d_in[0];
    const float* key   = (const float*)d_in[1];
    const float* value = (const float*)d_in[2];
    const float* Wq    = (const float*)d_in[3];
    const float* bq    = (const float*)d_in[4];
    const float* Wv    = (const float*)d_in[5];
    const float* bv    = (const float*)d_in[6];
    const float* avec  = (const float*)d_in[7];
    float* out = (float*)d_out;

    char* ws = (char*)d_ws;
    unsigned short* WqP = (unsigned short*)ws;               // 128 KB
    float* hqb     = (float*)(ws + 131072);                  // 32 KB
    float* s       = (float*)(ws + 163840);                  // 4 MB
    float* pml     = (float*)(ws + 4358144);                 // 16 KB
    float* sc      = (float*)(ws + 4374528);                 // 4 KB
    float* p_part  = (float*)(ws + 4378624);                 // 2 MB
    float* p_part2 = (float*)(ws + 6475776);                 // 2 MB (probe scratch)
    float* pml2    = (float*)(ws + 8572928);                 // 16 KB (probe scratch)

    prep_kernel<<<64, 256, 0, stream>>>(query, Wq, bq, WqP, hqb);
    // V0: real computation (NCH=32)
    fused_kernel<0><<<512, 256, 0, stream>>>(key, value, WqP, hqb, avec, s, p_part, pml, 32);
    // Ablation probes (NCH=16, outputs to scratch):
    fused_kernel<1><<<512, 256, 0, stream>>>(key, value, WqP, hqb, avec, p_part2, p_part2, pml2, 16);
    fused_kernel<2><<<512, 256, 0, stream>>>(key, value, WqP, hqb, avec, p_part2, p_part2, pml2, 16);
    fused_kernel<3><<<512, 256, 0, stream>>>(key, value, WqP, hqb, avec, p_part2, p_part2, pml2, 16);
    final_kernel<<<B_SZ * NUM_HEADS, 256, 0, stream>>>(p_part, pml, Wv, bv, out, sc);
    epass_kernel<<<B_SZ * 32, 256, 0, stream>>>(s, sc, out + B_SZ * HD);
}